// Round 1
// baseline (471.427 us; speedup 1.0000x reference)
//
#include <hip/hip_runtime.h>

// DFSMN: depthwise right-FIR (10 taps on future v) + order-19 left IIR, per (b,d) channel.
//   base[t] = (1+l0[d])*v[t] + sum_{k=1..10} r[k-1,d]*v[t+k]   (v zero-padded past T)
//   p[t]    = base[t] + sum_{j=1..19} l[j,d]*p[t-j]            (zero initial history)
//
// Parallelization: T split into NC=4 chunks of LC=512. Each chunk re-runs the
// recurrence from zero history WU=256 steps before its start and discards the
// warm-up outputs (IIR impulse response decays; worst-channel root ~0.97 ->
// truncation error <= 0.97^256 ~ 4e-4, threshold is 0.12). Chunk 0 is exact.
// 65536 threads = 1024 waves = 1 wave/SIMD chip-wide.

constexpr int T    = 2048;
constexpr int D    = 512;
constexpr int B    = 32;
constexpr int KR   = 10;   // right filter taps
constexpr int HIST = 19;   // Kl - 1 left history depth
constexpr int LC   = 512;  // chunk length
constexpr int NC   = T / LC;
constexpr int WU   = 256;  // warm-up steps (multiple of 8 for clean unroll)

__global__ __launch_bounds__(256, 1)
void dfsmn_kernel(const float* __restrict__ v,
                  const float* __restrict__ lfil,
                  const float* __restrict__ rfil,
                  float* __restrict__ out) {
    const int tid = threadIdx.x;
    const int blk = blockIdx.x;          // 256 blocks = (b, d-half, chunk)
    const int c   = blk & (NC - 1);      // chunk index 0..3 (uniform per block)
    const int bd  = blk / NC;            // 0..63
    const int d   = (bd & 1) * 256 + tid;
    const int b   = bd >> 1;

    const float* vp = v   + (size_t)b * T * D + d;   // stride D between t
    float*       op = out + (size_t)b * T * D + d;

    // Per-channel filter taps -> registers (30 loads, once).
    const float l0 = 1.0f + lfil[d];
    float lf[HIST];
#pragma unroll
    for (int j = 0; j < HIST; ++j) lf[j] = lfil[(j + 1) * D + d];
    float rf[KR];
#pragma unroll
    for (int k = 0; k < KR; ++k) rf[k] = rfil[k * D + d];

    const int t0    = c * LC;
    const int start = (t0 >= WU) ? (t0 - WU) : 0;   // chunk 0: no warm-up (exact)

    // p-history: hist[j] = p[t-1-j]
    float hist[HIST];
#pragma unroll
    for (int j = 0; j < HIST; ++j) hist[j] = 0.0f;

    // Sliding v window: w[j] = v[t+j]. max(start)+10 = 1290 < T: no guard here.
    float w[KR + 1];
#pragma unroll
    for (int j = 0; j <= KR; ++j) w[j] = vp[(size_t)(start + j) * D];

    // ---- warm-up: t in [start, t0), recurrence only, no stores ----
    // max load index t+1+KR <= t0+10 <= 1546 < T: no guard.
#pragma unroll 8
    for (int t = start; t < t0; ++t) {
        float p = l0 * w[0];
#pragma unroll
        for (int k = 0; k < KR; ++k) p += rf[k] * w[k + 1];
#pragma unroll
        for (int j = 0; j < HIST; ++j) p += lf[j] * hist[j];
#pragma unroll
        for (int j = HIST - 1; j > 0; --j) hist[j] = hist[j - 1];
        hist[0] = p;
#pragma unroll
        for (int j = 0; j < KR; ++j) w[j] = w[j + 1];
        w[KR] = vp[(size_t)(t + 1 + KR) * D];
    }

    // ---- main: t in [t0, t0+LC), store outputs ----
#pragma unroll 8
    for (int t = t0; t < t0 + LC; ++t) {
        float p = l0 * w[0];
#pragma unroll
        for (int k = 0; k < KR; ++k) p += rf[k] * w[k + 1];
#pragma unroll
        for (int j = 0; j < HIST; ++j) p += lf[j] * hist[j];
        op[(size_t)t * D] = p;
#pragma unroll
        for (int j = HIST - 1; j > 0; --j) hist[j] = hist[j - 1];
        hist[0] = p;
#pragma unroll
        for (int j = 0; j < KR; ++j) w[j] = w[j + 1];
        const int tn = t + 1 + KR;               // uniform across block -> scalar branch
        w[KR] = (tn < T) ? vp[(size_t)tn * D] : 0.0f;
    }
}

extern "C" void kernel_launch(void* const* d_in, const int* in_sizes, int n_in,
                              void* d_out, int out_size, void* d_ws, size_t ws_size,
                              hipStream_t stream) {
    const float* v  = (const float*)d_in[0];   // (B,1,T,D) fp32
    const float* lf = (const float*)d_in[1];   // (20,D)
    const float* rf = (const float*)d_in[2];   // (10,D)
    float* out = (float*)d_out;                // (B,1,T,D) fp32

    const int blocks = B * (D / 256) * NC;     // 32*2*4 = 256
    dfsmn_kernel<<<blocks, 256, 0, stream>>>(v, lf, rf, out);
}

// Round 2
// 283.532 us; speedup vs baseline: 1.6627x; 1.6627x over previous
//
#include <hip/hip_runtime.h>

// DFSMN: depthwise right-FIR (10 taps on future v) + order-19 left IIR, per (b,d) channel.
//   base[t] = (1+l0[d])*v[t] + sum_{k=1..10} r[k-1,d]*v[t+k]   (v zero-padded past T)
//   p[t]    = base[t] + sum_{j=1..19} l[j,d]*p[t-j]            (zero initial history)
//
// R1 -> R2 (latency-bound fix; R1: 322us, 8.8% HBM, 17.6% VALU, 10% occ):
//  * Group-of-8 prefetch: window w[0..18]=v[t..t+18]; 8 independent loads per group,
//    consumed >=8 iterations later -> 1 vmcnt wait per 8 steps (was 1 per step,
//    ~900cyc exposed HBM latency each).
//  * NC=8 chunks (LC=256, WU=256): 512 blocks -> 2 waves/SIMD TLP. Chunks 0,1 exact.
//  * 4-accumulator FMA split: per-step dependent chain ~120cyc -> ~40cyc.

constexpr int T    = 2048;
constexpr int D    = 512;
constexpr int B    = 32;
constexpr int KR   = 10;   // right filter taps
constexpr int HIST = 19;   // Kl - 1 left history depth
constexpr int LC   = 256;  // chunk length
constexpr int NC   = T / LC;      // 8
constexpr int WU   = 256;  // warm-up steps
constexpr int G    = 8;    // prefetch group size
constexpr int WIN  = KR + 1 + G;  // 19-wide sliding window

__device__ __forceinline__ float dfsmn_step(float l0, const float* rf, const float* lf,
                                            const float* w, int s, const float* hist) {
    float a0 = l0 * w[s];
    float a1 = rf[0] * w[s + 1];
    float a2 = rf[1] * w[s + 2];
    float a3 = rf[2] * w[s + 3];
    a0 += rf[3] * w[s + 4];
    a1 += rf[4] * w[s + 5];
    a2 += rf[5] * w[s + 6];
    a3 += rf[6] * w[s + 7];
    a0 += rf[7] * w[s + 8];
    a1 += rf[8] * w[s + 9];
    a2 += rf[9] * w[s + 10];
#pragma unroll
    for (int j = 0; j < HIST; ++j) {
        if ((j & 3) == 0)      a0 += lf[j] * hist[j];
        else if ((j & 3) == 1) a1 += lf[j] * hist[j];
        else if ((j & 3) == 2) a2 += lf[j] * hist[j];
        else                   a3 += lf[j] * hist[j];
    }
    return (a0 + a1) + (a2 + a3);
}

__global__ __launch_bounds__(256, 2)
void dfsmn_kernel(const float* __restrict__ v,
                  const float* __restrict__ lfil,
                  const float* __restrict__ rfil,
                  float* __restrict__ out) {
    const int tid = threadIdx.x;
    const int blk = blockIdx.x;          // 512 blocks = (b, d-half, chunk)
    const int c   = blk & (NC - 1);      // chunk index (uniform per block)
    const int bd  = blk / NC;            // 0..63
    const int d   = (bd & 1) * 256 + tid;
    const int b   = bd >> 1;

    const float* vp = v   + (size_t)b * T * D + d;   // stride D between t
    float*       op = out + (size_t)b * T * D + d;

    const float l0 = 1.0f + lfil[d];
    float lf[HIST];
#pragma unroll
    for (int j = 0; j < HIST; ++j) lf[j] = lfil[(j + 1) * D + d];
    float rf[KR];
#pragma unroll
    for (int k = 0; k < KR; ++k) rf[k] = rfil[k * D + d];

    const int t0    = c * LC;
    const int start = (t0 >= WU) ? (t0 - WU) : 0;   // chunks 0,1: exact

    float hist[HIST];                    // hist[j] = p[t-1-j]
#pragma unroll
    for (int j = 0; j < HIST; ++j) hist[j] = 0.0f;

    // Window invariant: w[j] = v[t+j]. start+WIN-1 <= 1536+18 < T: no guard.
    float w[WIN];
#pragma unroll
    for (int j = 0; j < WIN; ++j) w[j] = vp[(size_t)(start + j) * D];

    // ---- warm-up: t in [start, t0), no stores ----
    // prefetch idx max = t0 + WIN - 1 <= 1792+18 < T: no guard.
    for (int tg = start; tg < t0; tg += G) {
        float pf[G];
#pragma unroll
        for (int i = 0; i < G; ++i) pf[i] = vp[(size_t)(tg + WIN + i) * D];
#pragma unroll
        for (int s = 0; s < G; ++s) {
            const float p = dfsmn_step(l0, rf, lf, w, s, hist);
#pragma unroll
            for (int j = HIST - 1; j > 0; --j) hist[j] = hist[j - 1];
            hist[0] = p;
        }
#pragma unroll
        for (int j = 0; j < WIN - G; ++j) w[j] = w[j + G];
#pragma unroll
        for (int i = 0; i < G; ++i) w[WIN - G + i] = pf[i];
    }

    // ---- main: t in [t0, t0+LC), store outputs ----
    for (int tg = t0; tg < t0 + LC; tg += G) {
        float pf[G];
#pragma unroll
        for (int i = 0; i < G; ++i) {
            const int idx = tg + WIN + i;        // uniform per block -> scalar select
            pf[i] = (idx < T) ? vp[(size_t)idx * D] : 0.0f;
        }
#pragma unroll
        for (int s = 0; s < G; ++s) {
            const float p = dfsmn_step(l0, rf, lf, w, s, hist);
            op[(size_t)(tg + s) * D] = p;
#pragma unroll
            for (int j = HIST - 1; j > 0; --j) hist[j] = hist[j - 1];
            hist[0] = p;
        }
#pragma unroll
        for (int j = 0; j < WIN - G; ++j) w[j] = w[j + G];
#pragma unroll
        for (int i = 0; i < G; ++i) w[WIN - G + i] = pf[i];
    }
}

extern "C" void kernel_launch(void* const* d_in, const int* in_sizes, int n_in,
                              void* d_out, int out_size, void* d_ws, size_t ws_size,
                              hipStream_t stream) {
    const float* v  = (const float*)d_in[0];   // (B,1,T,D) fp32
    const float* lf = (const float*)d_in[1];   // (20,D)
    const float* rf = (const float*)d_in[2];   // (10,D)
    float* out = (float*)d_out;                // (B,1,T,D) fp32

    const int blocks = B * (D / 256) * NC;     // 32*2*8 = 512
    dfsmn_kernel<<<blocks, 256, 0, stream>>>(v, lf, rf, out);
}

// Round 3
// 270.425 us; speedup vs baseline: 1.7433x; 1.0485x over previous
//
#include <hip/hip_runtime.h>

// DFSMN: depthwise right-FIR (10 taps on future v) + order-19 left IIR, per (b,d) channel.
//   base[t] = (1+l0[d])*v[t] + sum_{k=1..10} r[k-1,d]*v[t+k]   (v zero-padded past T)
//   p[t]    = base[t] + sum_{j=1..19} l[j,d]*p[t-j]            (zero initial history)
//
// R2 -> R3 (VALU-waste fix; R2: 126us kernel, VALUBusy 51%, ~21 mov/step on
// hist/window shifts because unroll(8) != period(19)):
//  * Group size G = 19 = history period. p[t] lives in slot (t-start) mod 19,
//    all indices compile-time static -> hist rotation costs ZERO movs. After each
//    19-step group the register mapping is back to canonical.
//  * Warm-up = 13 groups = 247 steps (error ~0.02 vs 0.0156 at WU=256; thr 0.12).
//  * Main = 13 groups + 9-step tail (tail needs no canonical restore: kernel ends).
//  * Window w[0..28] = v[t..t+28]; 19 prefetch loads per group, consumed one full
//    group (~1300 cyc) later -> HBM latency (~900) covered.
//  * 4-way accumulator split keeps the per-step dependent chain ~40 cyc.

constexpr int T   = 2048;
constexpr int D   = 512;
constexpr int B   = 32;
constexpr int KR  = 10;        // right filter taps
constexpr int P   = 19;        // history depth == rotation period
constexpr int LC  = 256;       // chunk length
constexpr int NC  = T / LC;    // 8 chunks
constexpr int WG  = 13;        // warm-up groups (13*19 = 247 steps)
constexpr int MG  = 13;        // main full groups (247 steps)
constexpr int MT  = LC - MG * P;  // main tail = 9 steps
constexpr int WIN = KR + P;    // 29-register sliding window: w[j] = v[t+j]

// One recurrence step at compile-time group offset `s` (0..P-1).
// Window invariant: w[j] = v[tg + j]. History: p[t'] lives in h[(t'-start) % P],
// and (t - start) ≡ s (mod P) at this step. Reads all 19 slots (incl. slot s,
// which holds p[t-19]) BEFORE writing p[t] into slot s.
#define DFSMN_STEP(s, STORE_EXPR)                                              \
  {                                                                            \
    float a0 = l0 * w[(s)];                                                    \
    float a1 = rf[0] * w[(s) + 1];                                             \
    float a2 = rf[1] * w[(s) + 2];                                             \
    float a3 = rf[2] * w[(s) + 3];                                             \
    a0 += rf[3] * w[(s) + 4];                                                  \
    a1 += rf[4] * w[(s) + 5];                                                  \
    a2 += rf[5] * w[(s) + 6];                                                  \
    a3 += rf[6] * w[(s) + 7];                                                  \
    a0 += rf[7] * w[(s) + 8];                                                  \
    a1 += rf[8] * w[(s) + 9];                                                  \
    a2 += rf[9] * w[(s) + 10];                                                 \
    _Pragma("unroll")                                                          \
    for (int j = 0; j < P; ++j) {                                              \
      const int u = ((s) - 1 - j + 2 * P) % P;                                 \
      if ((j & 3) == 0)      a0 += lf[j] * h[u];                               \
      else if ((j & 3) == 1) a1 += lf[j] * h[u];                               \
      else if ((j & 3) == 2) a2 += lf[j] * h[u];                               \
      else                   a3 += lf[j] * h[u];                               \
    }                                                                          \
    const float p = (a0 + a1) + (a2 + a3);                                     \
    STORE_EXPR;                                                                \
    h[(s)] = p;                                                                \
  }

__global__ __launch_bounds__(256, 2)
void dfsmn_kernel(const float* __restrict__ v,
                  const float* __restrict__ lfil,
                  const float* __restrict__ rfil,
                  float* __restrict__ out) {
    const int tid = threadIdx.x;
    const int blk = blockIdx.x;          // 512 blocks = (b, d-half, chunk)
    const int c   = blk & (NC - 1);      // chunk index (uniform per block)
    const int bd  = blk / NC;            // 0..63
    const int d   = (bd & 1) * 256 + tid;
    const int b   = bd >> 1;

    const float* vp = v   + (size_t)b * T * D + d;   // stride D between t
    float*       op = out + (size_t)b * T * D + d;

    const float l0 = 1.0f + lfil[d];
    float lf[P];
#pragma unroll
    for (int j = 0; j < P; ++j) lf[j] = lfil[(j + 1) * D + d];
    float rf[KR];
#pragma unroll
    for (int k = 0; k < KR; ++k) rf[k] = rfil[k * D + d];

    const int t0    = c * LC;
    const int start = (c == 0) ? 0 : t0 - WG * P;   // chunk 0: exact, no warm-up
    const int nwarm = (c == 0) ? 0 : WG;

    float h[P];                          // circular history, all-zero init
#pragma unroll
    for (int j = 0; j < P; ++j) h[j] = 0.0f;

    // Window fill: start+28 <= 1792-247+28 < T always; chunk 7 start = 1545. OK.
    float w[WIN];
#pragma unroll
    for (int j = 0; j < WIN; ++j) w[j] = vp[(size_t)(start + j) * D];

    int tg = start;

    // ---- warm-up: nwarm groups of P steps, no stores ----
    // prefetch idx max = (t0-19) + 29 + 18 = t0 + 28 <= 1820 < T: no guard.
    for (int g = 0; g < nwarm; ++g) {
        float pf[P];
#pragma unroll
        for (int i = 0; i < P; ++i) pf[i] = vp[(size_t)(tg + WIN + i) * D];
#pragma unroll
        for (int s = 0; s < P; ++s) DFSMN_STEP(s, (void)0)
#pragma unroll
        for (int j = 0; j < WIN - P; ++j) w[j] = w[j + P];
#pragma unroll
        for (int i = 0; i < P; ++i) w[WIN - P + i] = pf[i];
        tg += P;
    }

    // ---- main: MG full groups with stores ----
    for (int g = 0; g < MG; ++g) {
        float pf[P];
#pragma unroll
        for (int i = 0; i < P; ++i) {
            const int idx = tg + WIN + i;          // uniform -> scalar branch
            pf[i] = (idx < T) ? vp[(size_t)idx * D] : 0.0f;
        }
#pragma unroll
        for (int s = 0; s < P; ++s) DFSMN_STEP(s, op[(size_t)(tg + s) * D] = p)
#pragma unroll
        for (int j = 0; j < WIN - P; ++j) w[j] = w[j + P];
#pragma unroll
        for (int i = 0; i < P; ++i) w[WIN - P + i] = pf[i];
        tg += P;
    }

    // ---- tail: MT steps; w[0..28] covers v[tg..tg+28], s+10 <= 18. ----
    // Rotation continues (s = 0..MT-1 of a fresh period); no restore needed.
#pragma unroll
    for (int s = 0; s < MT; ++s) DFSMN_STEP(s, op[(size_t)(tg + s) * D] = p)
}

extern "C" void kernel_launch(void* const* d_in, const int* in_sizes, int n_in,
                              void* d_out, int out_size, void* d_ws, size_t ws_size,
                              hipStream_t stream) {
    const float* v  = (const float*)d_in[0];   // (B,1,T,D) fp32
    const float* lf = (const float*)d_in[1];   // (20,D)
    const float* rf = (const float*)d_in[2];   // (10,D)
    float* out = (float*)d_out;                // (B,1,T,D) fp32

    const int blocks = B * (D / 256) * NC;     // 32*2*8 = 512
    dfsmn_kernel<<<blocks, 256, 0, stream>>>(v, lf, rf, out);
}